// Round 1
// baseline (546.236 us; speedup 1.0000x reference)
//
#include <hip/hip_runtime.h>

typedef __attribute__((ext_vector_type(8))) short bfrag8;   // 8 x bf16 (4 VGPRs)
typedef __attribute__((ext_vector_type(4))) float f32x4;    // MFMA accumulator

typedef const unsigned int __attribute__((address_space(1)))* gas1_u32;
typedef unsigned int __attribute__((address_space(3)))* gas3_u32;

#define DEV __device__ __forceinline__

DEV unsigned short f2bf(float f) {              // f32 -> bf16 bits, RNE
  unsigned int u = __builtin_bit_cast(unsigned int, f);
  u += 0x7fffu + ((u >> 16) & 1u);
  return (unsigned short)(u >> 16);
}

DEV void gload_lds16(const void* g, void* l) {  // async global->LDS, 16B/lane
  __builtin_amdgcn_global_load_lds((gas1_u32)g, (gas3_u32)l, 16, 0, 0);
}

// ---------------- per-row stats of x + raw bf16 cast (one wave per row) ---------------
__global__ __launch_bounds__(256) void k_xstats(
    const float* __restrict__ x, unsigned short* __restrict__ xb,
    float* __restrict__ mu, float* __restrict__ rstd)
{
  const int wid = threadIdx.x >> 6, lane = threadIdx.x & 63;
  const int row = blockIdx.x * 4 + wid;
  const float* base = x + (size_t)row * 1024;
  float4 v[4];
  #pragma unroll
  for (int i = 0; i < 4; ++i) v[i] = ((const float4*)base)[i * 64 + lane];
  float s = 0.f, q = 0.f;
  #pragma unroll
  for (int i = 0; i < 4; ++i) {
    s += v[i].x + v[i].y + v[i].z + v[i].w;
    q += v[i].x*v[i].x + v[i].y*v[i].y + v[i].z*v[i].z + v[i].w*v[i].w;
  }
  #pragma unroll
  for (int off = 32; off >= 1; off >>= 1) { s += __shfl_xor(s, off); q += __shfl_xor(q, off); }
  const float m  = s * (1.0f/1024.0f);
  const float var = q * (1.0f/1024.0f) - m * m;
  const float rs = rsqrtf(var + 1e-5f);
  if (lane == 0) { mu[row] = m; rstd[row] = rs; }
  unsigned short* ob = xb + (size_t)row * 1024;
  #pragma unroll
  for (int i = 0; i < 4; ++i) {
    ushort4 o;
    o.x = f2bf(v[i].x); o.y = f2bf(v[i].y); o.z = f2bf(v[i].z); o.w = f2bf(v[i].w);
    ((ushort4*)ob)[i * 64 + lane] = o;
  }
}

// ---------------- full LN of latents -> bf16 (block per row of 2048) ---------------
__global__ __launch_bounds__(256) void k_lnlat(
    const float* __restrict__ lat, const float* __restrict__ w,
    const float* __restrict__ b, unsigned short* __restrict__ ln)
{
  const int row = blockIdx.x, tid = threadIdx.x;
  const float* base = lat + (size_t)row * 2048;
  const float4 v0 = ((const float4*)base)[tid];
  const float4 v1 = ((const float4*)base)[256 + tid];
  float s = v0.x+v0.y+v0.z+v0.w + v1.x+v1.y+v1.z+v1.w;
  float q = v0.x*v0.x+v0.y*v0.y+v0.z*v0.z+v0.w*v0.w
          + v1.x*v1.x+v1.y*v1.y+v1.z*v1.z+v1.w*v1.w;
  #pragma unroll
  for (int off = 32; off >= 1; off >>= 1) { s += __shfl_xor(s, off); q += __shfl_xor(q, off); }
  __shared__ float red[8];
  const int wid = tid >> 6, lane = tid & 63;
  if (lane == 0) { red[wid] = s; red[4 + wid] = q; }
  __syncthreads();
  s = red[0] + red[1] + red[2] + red[3];
  q = red[4] + red[5] + red[6] + red[7];
  const float m  = s * (1.0f/2048.0f);
  const float var = q * (1.0f/2048.0f) - m * m;
  const float rs = rsqrtf(var + 1e-5f);
  const float4 w0 = ((const float4*)w)[tid], w1 = ((const float4*)w)[256 + tid];
  const float4 b0 = ((const float4*)b)[tid], b1 = ((const float4*)b)[256 + tid];
  ushort4 o0, o1;
  o0.x = f2bf((v0.x - m) * rs * w0.x + b0.x);
  o0.y = f2bf((v0.y - m) * rs * w0.y + b0.y);
  o0.z = f2bf((v0.z - m) * rs * w0.z + b0.z);
  o0.w = f2bf((v0.w - m) * rs * w0.w + b0.w);
  o1.x = f2bf((v1.x - m) * rs * w1.x + b1.x);
  o1.y = f2bf((v1.y - m) * rs * w1.y + b1.y);
  o1.z = f2bf((v1.z - m) * rs * w1.z + b1.z);
  o1.w = f2bf((v1.w - m) * rs * w1.w + b1.w);
  ((ushort4*)(ln + (size_t)row * 2048))[tid] = o0;
  ((ushort4*)(ln + (size_t)row * 2048))[256 + tid] = o1;
}

// ---------------- tiled transpose + bf16 cast: src[K][N] f32 -> dst[N][K] bf16 --------
__global__ __launch_bounds__(256) void k_transpose_cast(
    const float* __restrict__ src, unsigned short* __restrict__ dst,
    int K, int N, const float* __restrict__ rowscale, float scale)
{
  __shared__ float tile[32][33];
  const int tx = threadIdx.x & 31, ty = threadIdx.x >> 5;
  const int ntiles = N >> 5;
  const int k0 = (blockIdx.x / ntiles) << 5;
  const int n0 = (blockIdx.x % ntiles) << 5;
  #pragma unroll
  for (int r = 0; r < 4; ++r) {
    const int kk = ty + r * 8;
    float v = src[(size_t)(k0 + kk) * N + n0 + tx] * scale;
    if (rowscale) v *= rowscale[k0 + kk];
    tile[kk][tx] = v;
  }
  __syncthreads();
  #pragma unroll
  for (int r = 0; r < 4; ++r) {
    const int nn = ty + r * 8;
    dst[(size_t)(n0 + nn) * K + k0 + tx] = f2bf(tile[tx][nn]);
  }
}

// ---------------- c1[n]=sum_k w[k]*Wkv[k][n], c2[n]=sum_k b[k]*Wkv[k][n] ---------------
__global__ __launch_bounds__(256) void k_c1c2(
    const float* __restrict__ Wkv, const float* __restrict__ w,
    const float* __restrict__ b, float* __restrict__ c1, float* __restrict__ c2)
{
  const int n = blockIdx.x * 256 + threadIdx.x;
  float s1 = 0.f, s2 = 0.f;
  for (int k = 0; k < 1024; ++k) {
    const float wv = Wkv[(size_t)k * 1024 + n];
    s1 += w[k] * wv;
    s2 += b[k] * wv;
  }
  c1[n] = s1; c2[n] = s2;
}

// ---------------- batched GEMM: C[bt] = A[bt] (Mb x K, bf16) @ Bt^T ([N][K] bf16) ------
// MODE 0: kv epilogue  kv = rstd*(acc - mu*c1) + c2  -> bf16
// MODE 1: plain -> bf16        MODE 2: plain -> f32
template<int BM, int BN, int BK, int WR, int WC, int MODE>
__global__ __launch_bounds__(256) void k_gemm(
    const unsigned short* __restrict__ A, int lda,
    const unsigned short* __restrict__ Bt, int ldb,
    int Mb, int K, int mtiles, int ntiles,
    void* __restrict__ Cout, int ldc,
    const float* __restrict__ mu, const float* __restrict__ rstd,
    const float* __restrict__ c1, const float* __restrict__ c2)
{
  constexpr int MF = (BM / WR) / 16;
  constexpr int NF = (BN / WC) / 16;
  constexpr int KS = BK / 32;
  constexpr int RA = (BM * BK * 2) / 4096;
  constexpr int RB = (BN * BK * 2) / 4096;
  constexpr int RSH = (BK == 32) ? 6 : 7;       // log2(BK*2)
  constexpr int SWZ = (BK == 64) ? 64 : 0;      // byte XOR for BK=64 bank-granule spread

  __shared__ __attribute__((aligned(16))) unsigned short As[BM * BK];
  __shared__ __attribute__((aligned(16))) unsigned short Bs[BN * BK];

  const int bid = blockIdx.x;
  const int per_bt = mtiles * ntiles;
  const int bt = bid / per_bt;
  const int r  = bid % per_bt;
  const int nt = r / mtiles, mt = r % mtiles;   // mt fastest -> XCD keeps A panel in L2
  const int tid = threadIdx.x;
  const int wid = tid >> 6, lane = tid & 63;
  const int g = lane >> 4, c = lane & 15;
  const int wr = wid / WC, wc = wid % WC;
  const int MO = wr * (BM / WR), NO = wc * (BN / WC);

  const size_t abase = ((size_t)bt * Mb + (size_t)mt * BM) * lda;
  const size_t bbase = (size_t)nt * BN * ldb;

  const f32x4 zz = {0.f, 0.f, 0.f, 0.f};
  f32x4 acc[MF][NF];
  #pragma unroll
  for (int m = 0; m < MF; ++m)
    #pragma unroll
    for (int n = 0; n < NF; ++n) acc[m][n] = zz;

  const int nk = K / BK;
  for (int kt = 0; kt < nk; ++kt) {
    #pragma unroll
    for (int i = 0; i < RA; ++i) {
      const int lo = (i * 4 + wid) * 1024;
      const int o = lo + lane * 16;
      const int row = o >> RSH;
      const int colb = (o & (BK * 2 - 1)) ^ ((row & 1) * SWZ);
      gload_lds16((const char*)(A + abase + (size_t)row * lda + (size_t)kt * BK) + colb,
                  (char*)As + lo);
    }
    #pragma unroll
    for (int i = 0; i < RB; ++i) {
      const int lo = (i * 4 + wid) * 1024;
      const int o = lo + lane * 16;
      const int row = o >> RSH;
      const int colb = (o & (BK * 2 - 1)) ^ ((row & 1) * SWZ);
      gload_lds16((const char*)(Bt + bbase + (size_t)row * ldb + (size_t)kt * BK) + colb,
                  (char*)Bs + lo);
    }
    __syncthreads();
    #pragma unroll
    for (int kk = 0; kk < KS; ++kk) {
      bfrag8 af[MF], bfr[NF];
      #pragma unroll
      for (int m = 0; m < MF; ++m) {
        const int rw = MO + m * 16 + c;
        const int kc = ((kk * 32) ^ ((rw & 1) * (SWZ / 2))) + g * 8;
        af[m] = *(const bfrag8*)(As + rw * BK + kc);
      }
      #pragma unroll
      for (int n = 0; n < NF; ++n) {
        const int rw = NO + n * 16 + c;
        const int kc = ((kk * 32) ^ ((rw & 1) * (SWZ / 2))) + g * 8;
        bfr[n] = *(const bfrag8*)(Bs + rw * BK + kc);
      }
      #pragma unroll
      for (int m = 0; m < MF; ++m)
        #pragma unroll
        for (int n = 0; n < NF; ++n)
          acc[m][n] = __builtin_amdgcn_mfma_f32_16x16x32_bf16(af[m], bfr[n], acc[m][n], 0, 0, 0);
    }
    __syncthreads();
  }

  #pragma unroll
  for (int m = 0; m < MF; ++m) {
    #pragma unroll
    for (int j = 0; j < 4; ++j) {
      const int grow = mt * BM + MO + m * 16 + g * 4 + j;
      const size_t orow = (size_t)bt * Mb + grow;
      float rs = 0.f, muv = 0.f;
      if constexpr (MODE == 0) { rs = rstd[orow]; muv = mu[orow]; }
      #pragma unroll
      for (int n = 0; n < NF; ++n) {
        const int gcol = nt * BN + NO + n * 16 + c;
        float v = acc[m][n][j];
        if constexpr (MODE == 0) v = rs * (v - muv * c1[gcol]) + c2[gcol];
        if constexpr (MODE == 2) ((float*)Cout)[orow * ldc + gcol] = v;
        else ((unsigned short*)Cout)[orow * ldc + gcol] = f2bf(v);
      }
    }
  }
}

// ---------------- flash attention per (bt, head): 4 waves x 16 queries ----------------
// swapped QK^T (S^T = K @ Q^T) -> P is lane-local and directly forms PV A-fragment
__global__ __launch_bounds__(256) void k_attn(
    const unsigned short* __restrict__ q,   // [BT*64][512] bf16 (scale 1/8 pre-folded)
    const unsigned short* __restrict__ kv,  // [BT*1024][1024] bf16: k | v
    unsigned short* __restrict__ ao)        // [BT*64][512] bf16
{
  __shared__ __attribute__((aligned(16))) unsigned short Vt[64 * 64];  // [d][key] swizzled
  const int bid = blockIdx.x;
  const int bt = bid >> 3, h = bid & 7;
  const int tid = threadIdx.x;
  const int wid = tid >> 6, lane = tid & 63;
  const int g = lane >> 4, c = lane & 15;

  const size_t qoff = ((size_t)bt * 64 + wid * 16 + c) * 512 + h * 64;
  const bfrag8 qf0 = *(const bfrag8*)(q + qoff + g * 8);
  const bfrag8 qf1 = *(const bfrag8*)(q + qoff + 32 + g * 8);

  const f32x4 zz = {0.f, 0.f, 0.f, 0.f};
  f32x4 o[4] = {zz, zz, zz, zz};
  float m_run = -1e30f, l_run = 0.f;

  const size_t kvbase = (size_t)bt * 1024 * 1024;
  const unsigned short* kbase = kv + kvbase + h * 64;
  const unsigned short* vbase = kv + kvbase + 512 + h * 64;

  for (int ch = 0; ch < 16; ++ch) {            // 16 chunks of 64 keys
    #pragma unroll
    for (int rr = 0; rr < 2; ++rr) {           // stage V transposed + XOR-swizzled
      const int key = rr * 32 + (tid >> 3);
      const int d0 = (tid & 7) * 8;
      const bfrag8 vv = *(const bfrag8*)(vbase + (size_t)(ch * 64 + key) * 1024 + d0);
      #pragma unroll
      for (int j = 0; j < 8; ++j)
        Vt[(d0 + j) * 64 + (key ^ (j << 3))] = (unsigned short)vv[j];
    }
    __syncthreads();
    #pragma unroll
    for (int ks = 0; ks < 2; ++ks) {           // 2 x 32-key steps
      const int kb = ch * 64 + ks * 32;
      f32x4 s[2];
      #pragma unroll
      for (int t = 0; t < 2; ++t) {            // key permutation: row m -> key 8*(m>>2)+4t+(m&3)
        const int kr = ((c >> 2) << 3) + (t << 2) + (c & 3);
        const unsigned short* krow = kbase + (size_t)(kb + kr) * 1024;
        s[t] = zz;
        s[t] = __builtin_amdgcn_mfma_f32_16x16x32_bf16(*(const bfrag8*)(krow + g * 8),      qf0, s[t], 0, 0, 0);
        s[t] = __builtin_amdgcn_mfma_f32_16x16x32_bf16(*(const bfrag8*)(krow + 32 + g * 8), qf1, s[t], 0, 0, 0);
      }
      float pm = s[0][0];
      #pragma unroll
      for (int i = 1; i < 4; ++i) pm = fmaxf(pm, s[0][i]);
      #pragma unroll
      for (int i = 0; i < 4; ++i) pm = fmaxf(pm, s[1][i]);
      pm = fmaxf(pm, __shfl_xor(pm, 16));
      pm = fmaxf(pm, __shfl_xor(pm, 32));
      const float mn = fmaxf(m_run, pm);
      const float alpha = __expf(m_run - mn);
      float p[8];
      #pragma unroll
      for (int i = 0; i < 4; ++i) p[i]     = __expf(s[0][i] - mn);
      #pragma unroll
      for (int i = 0; i < 4; ++i) p[4 + i] = __expf(s[1][i] - mn);
      float ts = 0.f;
      #pragma unroll
      for (int i = 0; i < 8; ++i) ts += p[i];
      ts += __shfl_xor(ts, 16);
      ts += __shfl_xor(ts, 32);
      l_run = l_run * alpha + ts;
      m_run = mn;
      float ar[4];
      #pragma unroll
      for (int rj = 0; rj < 4; ++rj) ar[rj] = __shfl(alpha, g * 4 + rj);
      #pragma unroll
      for (int db = 0; db < 4; ++db)
        #pragma unroll
        for (int j = 0; j < 4; ++j) o[db][j] *= ar[j];
      bfrag8 pa;
      #pragma unroll
      for (int i = 0; i < 8; ++i) pa[i] = (short)f2bf(p[i]);
      #pragma unroll
      for (int db = 0; db < 4; ++db) {
        const int d = db * 16 + c;
        const bfrag8 vb = *(const bfrag8*)(Vt + d * 64 + ((ks * 32 + g * 8) ^ ((c & 7) << 3)));
        o[db] = __builtin_amdgcn_mfma_f32_16x16x32_bf16(pa, vb, o[db], 0, 0, 0);
      }
    }
    __syncthreads();
  }
  float lr[4];
  #pragma unroll
  for (int rj = 0; rj < 4; ++rj) lr[rj] = __shfl(l_run, g * 4 + rj);
  #pragma unroll
  for (int db = 0; db < 4; ++db)
    #pragma unroll
    for (int j = 0; j < 4; ++j) {
      const float val = o[db][j] / lr[j];
      ao[((size_t)bt * 64 + wid * 16 + g * 4 + j) * 512 + h * 64 + db * 16 + c] = f2bf(val);
    }
}

// --------------------------------- launch -------------------------------------------
extern "C" void kernel_launch(void* const* d_in, const int* in_sizes, int n_in,
                              void* d_out, int out_size, void* d_ws, size_t ws_size,
                              hipStream_t stream)
{
  const float* x    = (const float*)d_in[0];
  const float* lat  = (const float*)d_in[1];
  const float* nm_w = (const float*)d_in[2];
  const float* nm_b = (const float*)d_in[3];
  const float* nl_w = (const float*)d_in[4];
  const float* nl_b = (const float*)d_in[5];
  const float* Wq   = (const float*)d_in[6];
  const float* Wkv  = (const float*)d_in[7];
  const float* Wout = (const float*)d_in[8];

  char* p = (char*)d_ws;
  auto take = [&](size_t bytes) { char* r = p; p += (bytes + 255) & ~(size_t)255; return r; };
  unsigned short* xb    = (unsigned short*)take(64ull * 1024 * 1024 * 2);  // bf16(x)
  unsigned short* kvb   = (unsigned short*)take(64ull * 1024 * 1024 * 2);  // kv bf16
  unsigned short* lnb   = (unsigned short*)take(4096ull * 2048 * 2);       // LN(latents)
  unsigned short* qbuf  = (unsigned short*)take(4096ull * 512 * 2);        // q (scaled)
  unsigned short* aob   = (unsigned short*)take(4096ull * 512 * 2);        // attn out
  unsigned short* WqT   = (unsigned short*)take(512ull * 2048 * 2);
  unsigned short* WkvT  = (unsigned short*)take(1024ull * 1024 * 2);
  unsigned short* WoutT = (unsigned short*)take(2048ull * 512 * 2);
  float* muv = (float*)take(65536ull * 4);
  float* rsd = (float*)take(65536ull * 4);
  float* c1  = (float*)take(1024 * 4);
  float* c2  = (float*)take(1024 * 4);
  if ((size_t)(p - (char*)d_ws) > ws_size) return;  // insufficient workspace: fail loudly

  k_transpose_cast<<<dim3(64 * 16), 256, 0, stream>>>(Wq,   WqT,   2048,  512, nullptr, 0.125f);
  k_transpose_cast<<<dim3(32 * 32), 256, 0, stream>>>(Wkv,  WkvT,  1024, 1024, nm_w,    1.0f);
  k_transpose_cast<<<dim3(16 * 64), 256, 0, stream>>>(Wout, WoutT,  512, 2048, nullptr, 1.0f);
  k_c1c2<<<dim3(4), 256, 0, stream>>>(Wkv, nm_w, nm_b, c1, c2);
  k_xstats<<<dim3(16384), 256, 0, stream>>>(x, xb, muv, rsd);
  k_lnlat<<<dim3(4096), 256, 0, stream>>>(lat, nl_w, nl_b, lnb);

  // kv = LN(x) @ Wkv  (LN folded into epilogue), 64 x [1024x1024x1024]
  k_gemm<128, 128, 32, 2, 2, 0><<<dim3(4096), 256, 0, stream>>>(
      xb, 1024, WkvT, 1024, 1024, 1024, 8, 8, kvb, 1024, muv, rsd, c1, c2);
  // q = LN(latents) @ (Wq/8), 64 x [64x512x2048]
  k_gemm<64, 128, 64, 1, 4, 1><<<dim3(256), 256, 0, stream>>>(
      lnb, 2048, WqT, 2048, 64, 2048, 1, 4, qbuf, 512, nullptr, nullptr, nullptr, nullptr);

  k_attn<<<dim3(512), 256, 0, stream>>>(qbuf, kvb, aob);

  // out = attnout @ Wout, 64 x [64x2048x512] -> f32
  k_gemm<64, 128, 64, 1, 4, 2><<<dim3(1024), 256, 0, stream>>>(
      aob, 512, WoutT, 512, 64, 512, 1, 16, d_out, 2048, nullptr, nullptr, nullptr, nullptr);
}

// Round 2
// 375.179 us; speedup vs baseline: 1.4559x; 1.4559x over previous
//
#include <hip/hip_runtime.h>

typedef __attribute__((ext_vector_type(8))) short bfrag8;   // 8 x bf16 (4 VGPRs)
typedef __attribute__((ext_vector_type(4))) float f32x4;    // MFMA accumulator

typedef const unsigned int __attribute__((address_space(1)))* gas1_u32;
typedef unsigned int __attribute__((address_space(3)))* gas3_u32;

#define DEV __device__ __forceinline__

DEV unsigned short f2bf(float f) {              // f32 -> bf16 bits, RNE
  unsigned int u = __builtin_bit_cast(unsigned int, f);
  u += 0x7fffu + ((u >> 16) & 1u);
  return (unsigned short)(u >> 16);
}

DEV void gload_lds16(const void* g, void* l) {  // async global->LDS, 16B/lane
  __builtin_amdgcn_global_load_lds((gas1_u32)g, (gas3_u32)l, 16, 0, 0);
}

// ---------------- per-row stats of x + raw bf16 cast (one wave per row) ---------------
__global__ __launch_bounds__(256) void k_xstats(
    const float* __restrict__ x, unsigned short* __restrict__ xb,
    float* __restrict__ mu, float* __restrict__ rstd)
{
  const int wid = threadIdx.x >> 6, lane = threadIdx.x & 63;
  const int row = blockIdx.x * 4 + wid;
  const float* base = x + (size_t)row * 1024;
  float4 v[4];
  #pragma unroll
  for (int i = 0; i < 4; ++i) v[i] = ((const float4*)base)[i * 64 + lane];
  float s = 0.f, q = 0.f;
  #pragma unroll
  for (int i = 0; i < 4; ++i) {
    s += v[i].x + v[i].y + v[i].z + v[i].w;
    q += v[i].x*v[i].x + v[i].y*v[i].y + v[i].z*v[i].z + v[i].w*v[i].w;
  }
  #pragma unroll
  for (int off = 32; off >= 1; off >>= 1) { s += __shfl_xor(s, off); q += __shfl_xor(q, off); }
  const float m  = s * (1.0f/1024.0f);
  const float var = q * (1.0f/1024.0f) - m * m;
  const float rs = rsqrtf(var + 1e-5f);
  if (lane == 0) { mu[row] = m; rstd[row] = rs; }
  unsigned short* ob = xb + (size_t)row * 1024;
  #pragma unroll
  for (int i = 0; i < 4; ++i) {
    ushort4 o;
    o.x = f2bf(v[i].x); o.y = f2bf(v[i].y); o.z = f2bf(v[i].z); o.w = f2bf(v[i].w);
    ((ushort4*)ob)[i * 64 + lane] = o;
  }
}

// ---------------- full LN of latents -> bf16 (block per row of 2048) ---------------
__global__ __launch_bounds__(256) void k_lnlat(
    const float* __restrict__ lat, const float* __restrict__ w,
    const float* __restrict__ b, unsigned short* __restrict__ ln)
{
  const int row = blockIdx.x, tid = threadIdx.x;
  const float* base = lat + (size_t)row * 2048;
  const float4 v0 = ((const float4*)base)[tid];
  const float4 v1 = ((const float4*)base)[256 + tid];
  float s = v0.x+v0.y+v0.z+v0.w + v1.x+v1.y+v1.z+v1.w;
  float q = v0.x*v0.x+v0.y*v0.y+v0.z*v0.z+v0.w*v0.w
          + v1.x*v1.x+v1.y*v1.y+v1.z*v1.z+v1.w*v1.w;
  #pragma unroll
  for (int off = 32; off >= 1; off >>= 1) { s += __shfl_xor(s, off); q += __shfl_xor(q, off); }
  __shared__ float red[8];
  const int wid = tid >> 6, lane = tid & 63;
  if (lane == 0) { red[wid] = s; red[4 + wid] = q; }
  __syncthreads();
  s = red[0] + red[1] + red[2] + red[3];
  q = red[4] + red[5] + red[6] + red[7];
  const float m  = s * (1.0f/2048.0f);
  const float var = q * (1.0f/2048.0f) - m * m;
  const float rs = rsqrtf(var + 1e-5f);
  const float4 w0 = ((const float4*)w)[tid], w1 = ((const float4*)w)[256 + tid];
  const float4 b0 = ((const float4*)b)[tid], b1 = ((const float4*)b)[256 + tid];
  ushort4 o0, o1;
  o0.x = f2bf((v0.x - m) * rs * w0.x + b0.x);
  o0.y = f2bf((v0.y - m) * rs * w0.y + b0.y);
  o0.z = f2bf((v0.z - m) * rs * w0.z + b0.z);
  o0.w = f2bf((v0.w - m) * rs * w0.w + b0.w);
  o1.x = f2bf((v1.x - m) * rs * w1.x + b1.x);
  o1.y = f2bf((v1.y - m) * rs * w1.y + b1.y);
  o1.z = f2bf((v1.z - m) * rs * w1.z + b1.z);
  o1.w = f2bf((v1.w - m) * rs * w1.w + b1.w);
  ((ushort4*)(ln + (size_t)row * 2048))[tid] = o0;
  ((ushort4*)(ln + (size_t)row * 2048))[256 + tid] = o1;
}

// ---------------- tiled transpose + bf16 cast: src[K][N] f32 -> dst[N][K] bf16 --------
__global__ __launch_bounds__(256) void k_transpose_cast(
    const float* __restrict__ src, unsigned short* __restrict__ dst,
    int K, int N, const float* __restrict__ rowscale, float scale)
{
  __shared__ float tile[32][33];
  const int tx = threadIdx.x & 31, ty = threadIdx.x >> 5;
  const int ntiles = N >> 5;
  const int k0 = (blockIdx.x / ntiles) << 5;
  const int n0 = (blockIdx.x % ntiles) << 5;
  #pragma unroll
  for (int r = 0; r < 4; ++r) {
    const int kk = ty + r * 8;
    float v = src[(size_t)(k0 + kk) * N + n0 + tx] * scale;
    if (rowscale) v *= rowscale[k0 + kk];
    tile[kk][tx] = v;
  }
  __syncthreads();
  #pragma unroll
  for (int r = 0; r < 4; ++r) {
    const int nn = ty + r * 8;
    dst[(size_t)(n0 + nn) * K + k0 + tx] = f2bf(tile[tx][nn]);
  }
}

// ---------------- c1/c2 two-stage deterministic reduce -------------------------------
// part[(kc*2+0)][n] = sum_{k in chunk} w[k]*Wkv[k][n]; +1 for b
__global__ __launch_bounds__(256) void k_c1c2_part(
    const float* __restrict__ Wkv, const float* __restrict__ w,
    const float* __restrict__ b, float* __restrict__ part)
{
  const int kc = blockIdx.x;                 // 16 chunks of 64 k-rows
  const int n  = blockIdx.y * 256 + threadIdx.x;
  float s1 = 0.f, s2 = 0.f;
  const int k0 = kc * 64;
  for (int k = k0; k < k0 + 64; ++k) {
    const float wv = Wkv[(size_t)k * 1024 + n];
    s1 += w[k] * wv;
    s2 += b[k] * wv;
  }
  part[(size_t)(kc * 2 + 0) * 1024 + n] = s1;
  part[(size_t)(kc * 2 + 1) * 1024 + n] = s2;
}

__global__ __launch_bounds__(256) void k_c1c2_red(
    const float* __restrict__ part, float* __restrict__ c1, float* __restrict__ c2)
{
  const int n = blockIdx.x * 256 + threadIdx.x;
  float s1 = 0.f, s2 = 0.f;
  #pragma unroll
  for (int kc = 0; kc < 16; ++kc) {
    s1 += part[(size_t)(kc * 2 + 0) * 1024 + n];
    s2 += part[(size_t)(kc * 2 + 1) * 1024 + n];
  }
  c1[n] = s1; c2[n] = s2;
}

// ---------------- batched GEMM: C[bt] = A[bt] (Mb x K, bf16) @ Bt^T ([N][K] bf16) ------
// Double-buffered stage-ahead ("minimum 2-phase" T3 recipe): stage tile t+1 into the
// other buffer, compute tile t, ONE __syncthreads per K-tile (its vmcnt(0)+lgkmcnt(0)
// drain is exactly the required wait; loads were issued one full tile earlier).
// Distinct __shared__ arrays (As0/As1) so alias analysis keeps stage & read independent.
// MODE 0: kv epilogue  kv = rstd*(acc - mu*c1) + c2  -> bf16
// MODE 1: plain -> bf16        MODE 2: plain -> f32
template<int BM, int BN, int BK, int WM, int WN, int NT, int MODE>
__global__ __launch_bounds__(NT, 2) void k_gemm(
    const unsigned short* __restrict__ A, int lda,
    const unsigned short* __restrict__ Bt, int ldb,
    int Mb, int K, int mtiles, int ntiles,
    void* __restrict__ Cout, int ldc,
    const float* __restrict__ mu, const float* __restrict__ rstd,
    const float* __restrict__ c1, const float* __restrict__ c2)
{
  static_assert(BK == 64, "staging/swizzle assumes BK=64 (128B rows)");
  constexpr int NW = NT / 64;
  constexpr int MF = (BM / WM) / 16;
  constexpr int NF = (BN / WN) / 16;
  constexpr int KS = BK / 32;
  constexpr int LA = (BM * BK) / (8 * NT);   // 16B loads per thread for A tile
  constexpr int LB = (BN * BK) / (8 * NT);
  static_assert(WM * WN == NW, "wave grid");

  __shared__ __attribute__((aligned(16))) unsigned short As0[BM * BK];
  __shared__ __attribute__((aligned(16))) unsigned short As1[BM * BK];
  __shared__ __attribute__((aligned(16))) unsigned short Bs0[BN * BK];
  __shared__ __attribute__((aligned(16))) unsigned short Bs1[BN * BK];

  // bijective chunked XCD swizzle (nwg % 8 == 0 in all our launches)
  int bid = blockIdx.x;
  {
    const int nwg = gridDim.x;
    if ((nwg & 7) == 0) {
      const int q = nwg >> 3;
      bid = (bid & 7) * q + (bid >> 3);      // XCD k owns a contiguous logical chunk
    }
  }
  const int per_bt = mtiles * ntiles;
  const int bt = bid / per_bt;
  const int r  = bid % per_bt;
  const int mt = r / ntiles, nt = r % ntiles;  // nt fastest: consecutive share A panel
  const int tid = threadIdx.x;
  const int wid = tid >> 6, lane = tid & 63;
  const int g = lane >> 4, c = lane & 15;
  const int wr = wid / WN, wc = wid % WN;
  const int MO = wr * (BM / WM), NO = wc * (BN / WN);

  const size_t abase = ((size_t)bt * Mb + (size_t)mt * BM) * lda;
  const size_t bbase = (size_t)nt * BN * (size_t)ldb;

  const f32x4 zz = {0.f, 0.f, 0.f, 0.f};
  f32x4 acc[MF][NF];
  #pragma unroll
  for (int m = 0; m < MF; ++m)
    #pragma unroll
    for (int n = 0; n < NF; ++n) acc[m][n] = zz;

  auto stage = [&](unsigned short* da, unsigned short* db, int kt) {
    const unsigned short* ga = A + abase + (size_t)kt * BK;
    #pragma unroll
    for (int i = 0; i < LA; ++i) {
      const int o = (i * NT + tid) * 16;
      const int row = o >> 7;
      const int colb = (o & 127) ^ ((row & 3) << 5);   // 4-way bank spread, involution
      gload_lds16((const char*)(ga + (size_t)row * lda) + colb, (char*)da + o);
    }
    const unsigned short* gb = Bt + bbase + (size_t)kt * BK;
    #pragma unroll
    for (int i = 0; i < LB; ++i) {
      const int o = (i * NT + tid) * 16;
      const int row = o >> 7;
      const int colb = (o & 127) ^ ((row & 3) << 5);
      gload_lds16((const char*)(gb + (size_t)row * ldb) + colb, (char*)db + o);
    }
  };

  auto compute = [&](const unsigned short* as, const unsigned short* bs) {
    #pragma unroll
    for (int kk = 0; kk < KS; ++kk) {
      bfrag8 af[MF], bf[NF];
      #pragma unroll
      for (int m = 0; m < MF; ++m) {
        const int rw = MO + m * 16 + c;
        af[m] = *(const bfrag8*)((const char*)as + rw * (BK * 2)
                                 + ((kk * 64 + g * 16) ^ ((rw & 3) << 5)));
      }
      #pragma unroll
      for (int n = 0; n < NF; ++n) {
        const int rw = NO + n * 16 + c;
        bf[n] = *(const bfrag8*)((const char*)bs + rw * (BK * 2)
                                 + ((kk * 64 + g * 16) ^ ((rw & 3) << 5)));
      }
      #pragma unroll
      for (int m = 0; m < MF; ++m)
        #pragma unroll
        for (int n = 0; n < NF; ++n)
          acc[m][n] = __builtin_amdgcn_mfma_f32_16x16x32_bf16(af[m], bf[n], acc[m][n], 0, 0, 0);
    }
  };

  const int nkt = K / BK;                    // even for all our shapes (8/16/32)
  stage(As0, Bs0, 0);
  __syncthreads();
  for (int kt = 0; kt < nkt; kt += 2) {
    if (kt + 1 < nkt) stage(As1, Bs1, kt + 1);   // in flight during compute
    compute(As0, Bs0);
    __syncthreads();                              // drains vmcnt: tile kt+1 landed
    if (kt + 2 < nkt) stage(As0, Bs0, kt + 2);
    if (kt + 1 < nkt) compute(As1, Bs1);
    __syncthreads();
  }

  #pragma unroll
  for (int m = 0; m < MF; ++m) {
    #pragma unroll
    for (int j = 0; j < 4; ++j) {
      const int grow = mt * BM + MO + m * 16 + g * 4 + j;
      const size_t orow = (size_t)bt * Mb + grow;
      float rs = 0.f, muv = 0.f;
      if constexpr (MODE == 0) { rs = rstd[orow]; muv = mu[orow]; }
      #pragma unroll
      for (int n = 0; n < NF; ++n) {
        const int gcol = nt * BN + NO + n * 16 + c;
        float v = acc[m][n][j];
        if constexpr (MODE == 0) v = rs * (v - muv * c1[gcol]) + c2[gcol];
        if constexpr (MODE == 2) ((float*)Cout)[orow * ldc + gcol] = v;
        else ((unsigned short*)Cout)[orow * ldc + gcol] = f2bf(v);
      }
    }
  }
}

// ---------------- flash attention per (bt, head): 4 waves x 16 queries ----------------
// swapped QK^T (S^T = K @ Q^T) -> P is lane-local and directly forms PV A-fragment
__global__ __launch_bounds__(256) void k_attn(
    const unsigned short* __restrict__ q,   // [BT*64][512] bf16 (scale 1/8 pre-folded)
    const unsigned short* __restrict__ kv,  // [BT*1024][1024] bf16: k | v
    unsigned short* __restrict__ ao)        // [BT*64][512] bf16
{
  __shared__ __attribute__((aligned(16))) unsigned short Vt[64 * 64];  // [d][key] swizzled
  const int bid = blockIdx.x;
  const int bt = bid >> 3, h = bid & 7;
  const int tid = threadIdx.x;
  const int wid = tid >> 6, lane = tid & 63;
  const int g = lane >> 4, c = lane & 15;

  const size_t qoff = ((size_t)bt * 64 + wid * 16 + c) * 512 + h * 64;
  const bfrag8 qf0 = *(const bfrag8*)(q + qoff + g * 8);
  const bfrag8 qf1 = *(const bfrag8*)(q + qoff + 32 + g * 8);

  const f32x4 zz = {0.f, 0.f, 0.f, 0.f};
  f32x4 o[4] = {zz, zz, zz, zz};
  float m_run = -1e30f, l_run = 0.f;

  const size_t kvbase = (size_t)bt * 1024 * 1024;
  const unsigned short* kbase = kv + kvbase + h * 64;
  const unsigned short* vbase = kv + kvbase + 512 + h * 64;

  for (int ch = 0; ch < 16; ++ch) {            // 16 chunks of 64 keys
    #pragma unroll
    for (int rr = 0; rr < 2; ++rr) {           // stage V transposed + XOR-swizzled
      const int key = rr * 32 + (tid >> 3);
      const int d0 = (tid & 7) * 8;
      const bfrag8 vv = *(const bfrag8*)(vbase + (size_t)(ch * 64 + key) * 1024 + d0);
      #pragma unroll
      for (int j = 0; j < 8; ++j)
        Vt[(d0 + j) * 64 + (key ^ (j << 3))] = (unsigned short)vv[j];
    }
    __syncthreads();
    #pragma unroll
    for (int ks = 0; ks < 2; ++ks) {           // 2 x 32-key steps
      const int kb = ch * 64 + ks * 32;
      f32x4 s[2];
      #pragma unroll
      for (int t = 0; t < 2; ++t) {            // key permutation: row m -> key 8*(m>>2)+4t+(m&3)
        const int kr = ((c >> 2) << 3) + (t << 2) + (c & 3);
        const unsigned short* krow = kbase + (size_t)(kb + kr) * 1024;
        s[t] = zz;
        s[t] = __builtin_amdgcn_mfma_f32_16x16x32_bf16(*(const bfrag8*)(krow + g * 8),      qf0, s[t], 0, 0, 0);
        s[t] = __builtin_amdgcn_mfma_f32_16x16x32_bf16(*(const bfrag8*)(krow + 32 + g * 8), qf1, s[t], 0, 0, 0);
      }
      float pm = s[0][0];
      #pragma unroll
      for (int i = 1; i < 4; ++i) pm = fmaxf(pm, s[0][i]);
      #pragma unroll
      for (int i = 0; i < 4; ++i) pm = fmaxf(pm, s[1][i]);
      pm = fmaxf(pm, __shfl_xor(pm, 16));
      pm = fmaxf(pm, __shfl_xor(pm, 32));
      const float mn = fmaxf(m_run, pm);
      const float alpha = __expf(m_run - mn);
      float p[8];
      #pragma unroll
      for (int i = 0; i < 4; ++i) p[i]     = __expf(s[0][i] - mn);
      #pragma unroll
      for (int i = 0; i < 4; ++i) p[4 + i] = __expf(s[1][i] - mn);
      float ts = 0.f;
      #pragma unroll
      for (int i = 0; i < 8; ++i) ts += p[i];
      ts += __shfl_xor(ts, 16);
      ts += __shfl_xor(ts, 32);
      l_run = l_run * alpha + ts;
      m_run = mn;
      float ar[4];
      #pragma unroll
      for (int rj = 0; rj < 4; ++rj) ar[rj] = __shfl(alpha, g * 4 + rj);
      #pragma unroll
      for (int db = 0; db < 4; ++db)
        #pragma unroll
        for (int j = 0; j < 4; ++j) o[db][j] *= ar[j];
      bfrag8 pa;
      #pragma unroll
      for (int i = 0; i < 8; ++i) pa[i] = (short)f2bf(p[i]);
      #pragma unroll
      for (int db = 0; db < 4; ++db) {
        const int d = db * 16 + c;
        const bfrag8 vb = *(const bfrag8*)(Vt + d * 64 + ((ks * 32 + g * 8) ^ ((c & 7) << 3)));
        o[db] = __builtin_amdgcn_mfma_f32_16x16x32_bf16(pa, vb, o[db], 0, 0, 0);
      }
    }
    __syncthreads();
  }
  float lr[4];
  #pragma unroll
  for (int rj = 0; rj < 4; ++rj) lr[rj] = __shfl(l_run, g * 4 + rj);
  #pragma unroll
  for (int db = 0; db < 4; ++db)
    #pragma unroll
    for (int j = 0; j < 4; ++j) {
      const float val = o[db][j] / lr[j];
      ao[((size_t)bt * 64 + wid * 16 + g * 4 + j) * 512 + h * 64 + db * 16 + c] = f2bf(val);
    }
}

// --------------------------------- launch -------------------------------------------
extern "C" void kernel_launch(void* const* d_in, const int* in_sizes, int n_in,
                              void* d_out, int out_size, void* d_ws, size_t ws_size,
                              hipStream_t stream)
{
  const float* x    = (const float*)d_in[0];
  const float* lat  = (const float*)d_in[1];
  const float* nm_w = (const float*)d_in[2];
  const float* nm_b = (const float*)d_in[3];
  const float* nl_w = (const float*)d_in[4];
  const float* nl_b = (const float*)d_in[5];
  const float* Wq   = (const float*)d_in[6];
  const float* Wkv  = (const float*)d_in[7];
  const float* Wout = (const float*)d_in[8];

  char* p = (char*)d_ws;
  auto take = [&](size_t bytes) { char* r = p; p += (bytes + 255) & ~(size_t)255; return r; };
  unsigned short* xb    = (unsigned short*)take(64ull * 1024 * 1024 * 2);  // bf16(x)
  unsigned short* kvb   = (unsigned short*)take(64ull * 1024 * 1024 * 2);  // kv bf16
  unsigned short* lnb   = (unsigned short*)take(4096ull * 2048 * 2);       // LN(latents)
  unsigned short* qbuf  = (unsigned short*)take(4096ull * 512 * 2);        // q (scaled)
  unsigned short* aob   = (unsigned short*)take(4096ull * 512 * 2);        // attn out
  unsigned short* WqT   = (unsigned short*)take(512ull * 2048 * 2);
  unsigned short* WkvT  = (unsigned short*)take(1024ull * 1024 * 2);
  unsigned short* WoutT = (unsigned short*)take(2048ull * 512 * 2);
  float* muv  = (float*)take(65536ull * 4);
  float* rsd  = (float*)take(65536ull * 4);
  float* c1   = (float*)take(1024 * 4);
  float* c2   = (float*)take(1024 * 4);
  float* part = (float*)take(32ull * 1024 * 4);
  if ((size_t)(p - (char*)d_ws) > ws_size) return;  // insufficient workspace: fail loudly

  k_transpose_cast<<<dim3(64 * 16), 256, 0, stream>>>(Wq,   WqT,   2048,  512, nullptr, 0.125f);
  k_transpose_cast<<<dim3(32 * 32), 256, 0, stream>>>(Wkv,  WkvT,  1024, 1024, nm_w,    1.0f);
  k_transpose_cast<<<dim3(16 * 64), 256, 0, stream>>>(Wout, WoutT,  512, 2048, nullptr, 1.0f);
  k_c1c2_part<<<dim3(16, 4), 256, 0, stream>>>(Wkv, nm_w, nm_b, part);
  k_c1c2_red<<<dim3(4), 256, 0, stream>>>(part, c1, c2);
  k_xstats<<<dim3(16384), 256, 0, stream>>>(x, xb, muv, rsd);
  k_lnlat<<<dim3(4096), 256, 0, stream>>>(lat, nl_w, nl_b, lnb);

  // kv = LN(x) @ Wkv (LN folded into epilogue): 64 x [1024x1024x1024], 256^2 tile
  k_gemm<256, 256, 64, 2, 4, 512, 0><<<dim3(1024), 512, 0, stream>>>(
      xb, 1024, WkvT, 1024, 1024, 1024, 4, 4, kvb, 1024, muv, rsd, c1, c2);
  // q = LN(latents) @ (Wq/8): 64 x [64x512x2048]
  k_gemm<64, 128, 64, 1, 4, 256, 1><<<dim3(256), 256, 0, stream>>>(
      lnb, 2048, WqT, 2048, 64, 2048, 1, 4, qbuf, 512, nullptr, nullptr, nullptr, nullptr);

  k_attn<<<dim3(512), 256, 0, stream>>>(qbuf, kvb, aob);

  // out = attnout @ Wout: 64 x [64x2048x512] -> f32
  k_gemm<64, 128, 64, 1, 4, 256, 2><<<dim3(1024), 256, 0, stream>>>(
      aob, 512, WoutT, 512, 64, 512, 1, 16, d_out, 2048, nullptr, nullptr, nullptr, nullptr);
}